// Round 12
// baseline (6741.276 us; speedup 1.0000x reference)
//
#include <hip/hip_runtime.h>
#include <stdint.h>

// R12: R11 analysis says each step-phase is a ~3us SERIAL latency chain and
// R11 ran 2 chains serially per block. Fix: 512 blocks x 256 thr (2 blocks/CU,
// block = (8-unit strip, bq-group)); each block runs ONE phase per step and the
// CU scheduler overlaps the two co-resident blocks' chains (TLP across blocks).
// Protocol unchanged (R10/R11-proven): agent h store -> __syncthreads (vmcnt
// drain) -> flag store; consumer: poll flags -> sync -> agent h load.
// Also: out_h store moved after the flag store (off the drain path, R11
// regression fixed); xchg padded [16][33] (kills 4.2M LDS bank conflicts).

typedef unsigned short u16;
typedef __attribute__((ext_vector_type(8))) short bf16x8;
typedef __attribute__((ext_vector_type(2))) uint64_t u64x2;
typedef __attribute__((ext_vector_type(4))) float f32x4;

static __device__ __forceinline__ u16 f2b(float f) {
  uint32_t b = __float_as_uint(f);
  return (u16)((b + 0x7fffu + ((b >> 16) & 1u)) >> 16);  // RNE
}
static __device__ __forceinline__ uint64_t pack4(float4 v) {
  return (uint64_t)f2b(v.x) | ((uint64_t)f2b(v.y) << 16) |
         ((uint64_t)f2b(v.z) << 32) | ((uint64_t)f2b(v.w) << 48);
}
static __device__ __forceinline__ float b2f(u16 u) {
  return __uint_as_float(((uint32_t)u) << 16);
}
static __device__ __forceinline__ float sigm(float x) {
  return 1.0f / (1.0f + __expf(-x));
}
static __device__ __forceinline__ float tanh_(float x) {
  float e = __expf(2.0f * x);
  return 1.0f - 2.0f / (e + 1.0f);
}

// ---------------------------------------------------------------- prep kernels
__global__ __launch_bounds__(256) void transpose_w(const float* __restrict__ Wih,
                                                   const float* __restrict__ Whh,
                                                   u16* __restrict__ Tih,
                                                   u16* __restrict__ Thh) {
  __shared__ float tile[64][65];
  const float* src = blockIdx.z ? Whh : Wih;
  u16* dst = blockIdx.z ? Thh : Tih;
  int k0 = blockIdx.y * 64, n0 = blockIdx.x * 64;
  int tid = threadIdx.x;
#pragma unroll
  for (int i = 0; i < 16; ++i) {
    int idx = i * 256 + tid;
    int kl = idx >> 6, nl = idx & 63;
    tile[kl][nl] = src[(size_t)(k0 + kl) * 4096 + n0 + nl];
  }
  __syncthreads();
#pragma unroll
  for (int i = 0; i < 16; ++i) {
    int idx = i * 256 + tid;
    int nl = idx >> 6, kl = idx & 63;
    dst[(size_t)(n0 + nl) * 1024 + k0 + kl] = f2b(tile[kl][nl]);
  }
}

__global__ __launch_bounds__(256) void convert_h0(const float* __restrict__ h0,
                                                  u16* __restrict__ dst) {
  int i = blockIdx.x * 256 + threadIdx.x;  // 16384 float4s
  float4 v = ((const float4*)h0)[i];
  ((uint64_t*)dst)[i] = pack4(v);
}

// ------------------------------------------------------------------- big GEMM
// C[M][4096] bf16 = A[M][1024] f32 @ Bt[4096][1024]^T + bias. (unchanged, PASS)
__global__ __launch_bounds__(256) void gemm_xg(const float* __restrict__ A,
                                               const u16* __restrict__ Bt,
                                               const float* __restrict__ bias,
                                               u16* __restrict__ C) {
  __shared__ u16 sA[2][128 * 32];
  __shared__ u16 sB[2][128 * 32];
  const int tid = threadIdx.x;
  const int wave = tid >> 6, lane = tid & 63;
  const int bx = blockIdx.x, by = blockIdx.y;
  const int wr = wave >> 1, wc = wave & 1;
  const int lm = lane & 15, ko = (lane >> 4) * 8;

  const int ar = lane >> 1, ac = (lane & 1) * 16;
  const float* gA = A + (size_t)(by * 128 + wave * 32 + ar) * 1024 + ac;
  const u16* gB = Bt + (size_t)(bx * 128 + wave * 32 + (lane >> 2)) * 1024 + (lane & 3) * 8;
  const int bidx = wave * 1024 + (lane >> 2) * 32 + (lane & 3) * 8;

  f32x4 acc[4][4] = {};

  auto stage = [&](int kt, int buf) {
    const u16* gb = gB + kt * 32;
    bf16x8 b0 = *(const bf16x8*)gb;
    bf16x8 b1 = *(const bf16x8*)(gb + 16 * 1024);
    *(bf16x8*)&sB[buf][bidx] = b0;
    *(bf16x8*)&sB[buf][bidx + 512] = b1;
    const float* ga = gA + kt * 32;
    float4 v0 = *(const float4*)(ga + 0);
    float4 v1 = *(const float4*)(ga + 4);
    float4 v2 = *(const float4*)(ga + 8);
    float4 v3 = *(const float4*)(ga + 12);
    uint64_t* la = (uint64_t*)&sA[buf][wave * 1024 + ar * 32 + ac];
    la[0] = pack4(v0);
    la[1] = pack4(v1);
    la[2] = pack4(v2);
    la[3] = pack4(v3);
  };

  stage(0, 0);
  __syncthreads();
  int p = 0;
  for (int kt = 0; kt < 32; ++kt) {
    if (kt < 31) stage(kt + 1, p ^ 1);
    bf16x8 af[4], bfv[4];
#pragma unroll
    for (int i = 0; i < 4; ++i)
      af[i] = *(const bf16x8*)&sA[p][(wr * 64 + i * 16 + lm) * 32 + ko];
#pragma unroll
    for (int j = 0; j < 4; ++j)
      bfv[j] = *(const bf16x8*)&sB[p][(wc * 64 + j * 16 + lm) * 32 + ko];
#pragma unroll
    for (int i = 0; i < 4; ++i)
#pragma unroll
      for (int j = 0; j < 4; ++j)
        acc[i][j] = __builtin_amdgcn_mfma_f32_16x16x32_bf16(af[i], bfv[j], acc[i][j], 0, 0, 0);
    __syncthreads();
    p ^= 1;
  }

  float bj[4];
#pragma unroll
  for (int j = 0; j < 4; ++j)
    bj[j] = bias[bx * 128 + wc * 64 + j * 16 + lm];
#pragma unroll
  for (int i = 0; i < 4; ++i) {
    int row = by * 128 + wr * 64 + i * 16 + (lane >> 4) * 4;
#pragma unroll
    for (int j = 0; j < 4; ++j) {
      int col = bx * 128 + wc * 64 + j * 16 + lm;
#pragma unroll
      for (int r = 0; r < 4; ++r)
        C[(size_t)(row + r) * 4096 + col] = f2b(acc[i][j][r] + bj[j]);
    }
  }
}

// --------------------------------------- persistent fine-grain recurrence
// Grid 512 blocks (2/CU), block 256 (4 waves). bid: ub8=bid&127 (units
// ub8*8..+8), bq=bid>>7 (batch rows bq*16..+16). Gate-col c in [0,32):
// gate=c>>3, u=c&7. Wave w owns K-slice [w*256,+256): bfr[kk][nt] (64 VGPRs),
// nt tile covers cols nt*16..+16. Per step ONE phase; co-resident block's
// chain overlaps ours via the CU scheduler.
__global__ __launch_bounds__(256, 2) void recur_pers(
    const u16* __restrict__ xg,      // [W][64][4096] bf16, bias already added
    const u16* __restrict__ whh_t,   // [4096][1024] bf16
    u16* __restrict__ h_buf,         // [2][64][1024] bf16 ping-pong
    float* __restrict__ c_st,        // [64][1024] f32
    float* __restrict__ out_h,       // [512][64][1024] f32
    float* __restrict__ out_hT, float* __restrict__ out_cT,
    uint32_t* __restrict__ flags,    // [512][4][128] u32, zeroed once
    int t0, int W) {
  __shared__ float xchg[4][16][33];  // padded: conflict-free reduce

  const int tid = threadIdx.x;
  const int wave = tid >> 6, lane = tid & 63;
  const int bid = blockIdx.x;
  const int ub8 = bid & 127;
  const int bq = bid >> 7;
  const int lm = lane & 15, ko = (lane >> 4) * 8;

  // B-frags resident: col c = nt*16+lm -> whh_t row (c>>3)*1024 + ub8*8 + (c&7)
  bf16x8 bfr[8][2];
#pragma unroll
  for (int nt = 0; nt < 2; ++nt) {
    int c = nt * 16 + lm;
    const u16* bp =
        whh_t + (size_t)((c >> 3) * 1024 + ub8 * 8 + (c & 7)) * 1024 + wave * 256 + ko;
#pragma unroll
    for (int kk = 0; kk < 8; ++kk) bfr[kk][nt] = *(const bf16x8*)(bp + kk * 32);
  }

  // epilogue ownership: threads 0..127 -> (row r_b, unit u)
  const int r_b = tid >> 3, u = tid & 7;
  const int b = bq * 16 + r_b;
  const int unit = ub8 * 8 + u;
  float c_val = (tid < 128) ? c_st[b * 1024 + unit] : 0.f;

  for (int ts = 0; ts < W; ++ts) {
    const int t = t0 + ts;

    // ---- wait: previous step's 128 producer flags for this bq ----
    if (t > 0) {
      const uint32_t* fl = flags + ((size_t)(t - 1) * 4 + bq) * 128;
      if (wave == 3) {
        uint32_t spin = 0;
        for (; spin < (1u << 15); ++spin) {  // bounded: never wedge
          uint32_t v0 = __hip_atomic_load(fl + lane, __ATOMIC_RELAXED,
                                          __HIP_MEMORY_SCOPE_AGENT);
          uint32_t v1 = __hip_atomic_load(fl + 64 + lane, __ATOMIC_RELAXED,
                                          __HIP_MEMORY_SCOPE_AGENT);
          if (__all((v0 == 1u) & (v1 == 1u))) break;
          __builtin_amdgcn_s_sleep(1);
        }
        if (spin >= (1u << 15) && lane == 0)  // sentinel: absmax ~1e6
          out_h[(size_t)t * 65536 + bid] = 1.0e6f;
      }
      __syncthreads();
    }

    // ---- xg prefetch (independent of h) ----
    u16 xr0 = 0, xr1 = 0, xr2 = 0, xr3 = 0;
    if (tid < 128) {
      const u16* xgp = xg + ((size_t)ts * 64 + b) * 4096 + unit;
      xr0 = xgp[0];
      xr1 = xgp[1024];
      xr2 = xgp[2048];
      xr3 = xgp[3072];
    }

    // ---- A-frags: 8 x 16B per lane, agent-scope (L3 coherence point) ----
    const u16* ap = h_buf + (size_t)((t - 1) & 1) * 65536 +
                    (size_t)(bq * 16 + lm) * 1024 + wave * 256 + ko;
    bf16x8 a[8];
#pragma unroll
    for (int kk = 0; kk < 8; ++kk) {
      const uint64_t* p = (const uint64_t*)(ap + kk * 32);
      u64x2 v;
      v.x = __hip_atomic_load(p, __ATOMIC_RELAXED, __HIP_MEMORY_SCOPE_AGENT);
      v.y = __hip_atomic_load(p + 1, __ATOMIC_RELAXED, __HIP_MEMORY_SCOPE_AGENT);
      a[kk] = __builtin_bit_cast(bf16x8, v);
    }

    // ---- 2 independent 8-deep MFMA chains (nt tiles) ----
    f32x4 acc[2] = {{0.f, 0.f, 0.f, 0.f}, {0.f, 0.f, 0.f, 0.f}};
#pragma unroll
    for (int kk = 0; kk < 8; ++kk) {
#pragma unroll
      for (int nt = 0; nt < 2; ++nt)
        acc[nt] = __builtin_amdgcn_mfma_f32_16x16x32_bf16(a[kk], bfr[kk][nt], acc[nt], 0, 0, 0);
    }
    {
      int crow = (lane >> 4) * 4;  // C layout: col=lane&15, row=(lane>>4)*4+r
#pragma unroll
      for (int nt = 0; nt < 2; ++nt)
#pragma unroll
        for (int r = 0; r < 4; ++r) xchg[wave][crow + r][nt * 16 + lm] = acc[nt][r];
    }
    __syncthreads();

    float h_new = 0.f, c_new = 0.f;
    if (tid < 128) {
      float raw[4];
#pragma unroll
      for (int g = 0; g < 4; ++g) {
        int c = g * 8 + u;
        raw[g] = xchg[0][r_b][c] + xchg[1][r_b][c] + xchg[2][r_b][c] + xchg[3][r_b][c];
      }
      float ig = sigm(raw[0] + b2f(xr0));
      float fg = sigm(raw[1] + b2f(xr1));
      float gg = tanh_(raw[2] + b2f(xr2));
      float og = sigm(raw[3] + b2f(xr3));
      c_val = fg * c_val + ig * gg;
      c_new = c_val;
      h_new = og * tanh_(c_val);
      uint32_t mine = f2b(h_new);
      uint32_t other = __shfl_xor(mine, 1);
      if ((u & 1) == 0) {
        uint32_t pairv = mine | (other << 16);
        __hip_atomic_store(
            (uint32_t*)(h_buf + (size_t)(t & 1) * 65536 + (size_t)b * 1024 + unit), pairv,
            __ATOMIC_RELAXED, __HIP_MEMORY_SCOPE_AGENT);
      }
    }

    __syncthreads();  // vmcnt drain: h_buf stores globally visible
    if (tid == 0)
      __hip_atomic_store(flags + ((size_t)t * 4 + bq) * 128 + ub8, 1u, __ATOMIC_RELAXED,
                         __HIP_MEMORY_SCOPE_AGENT);
    // out_h (and final hT/cT) AFTER the flag: off the critical drain path
    if (tid < 128) {
      out_h[(size_t)t * 65536 + (size_t)b * 1024 + unit] = h_new;
      if (t == 511) {
        out_hT[b * 1024 + unit] = h_new;
        out_cT[b * 1024 + unit] = c_new;
      }
    }
  }

  if (tid < 128) c_st[b * 1024 + unit] = c_val;
}

// -------------------------------------------------------------------- launch
extern "C" void kernel_launch(void* const* d_in, const int* in_sizes, int n_in,
                              void* d_out, int out_size, void* d_ws, size_t ws_size,
                              hipStream_t stream) {
  const float* x = (const float*)d_in[0];
  const float* h0 = (const float*)d_in[1];
  const float* c0 = (const float*)d_in[2];
  const float* wih = (const float*)d_in[3];
  const float* whh = (const float*)d_in[4];
  const float* bias = (const float*)d_in[5];

  float* out = (float*)d_out;
  float* out_h = out;                              // [512][64][1024]
  float* out_hT = out + (size_t)512 * 64 * 1024;   // [64][1024]
  float* out_cT = out_hT + 64 * 1024;              // [64][1024]

  // adaptive xg window (bf16): W in {64,16,4}
  const size_t fixed = (size_t)2 * 4096 * 1024 * 2     // wih_t + whh_t
                       + (size_t)2 * 64 * 1024 * 2     // h_buf
                       + (size_t)64 * 1024 * 4         // c_state
                       + (size_t)512 * 4 * 128 * 4;    // flags (1MB)
  int W = 64;
  while (W > 4 && fixed + (size_t)W * 64 * 4096 * 2 > ws_size) W >>= 2;

  char* ws = (char*)d_ws;
  u16* wih_t = (u16*)ws;   ws += (size_t)4096 * 1024 * 2;    // 8MB
  u16* whh_t = (u16*)ws;   ws += (size_t)4096 * 1024 * 2;    // 8MB
  u16* xg = (u16*)ws;      ws += (size_t)W * 64 * 4096 * 2;  // <=32MB
  u16* h_buf = (u16*)ws;   ws += (size_t)2 * 64 * 1024 * 2;  // 256KB
  float* c_st = (float*)ws; ws += (size_t)64 * 1024 * 4;     // 256KB
  uint32_t* flags = (uint32_t*)ws;                           // 1MB

  hipMemsetAsync(flags, 0, (size_t)512 * 4 * 128 * 4, stream);
  convert_h0<<<64, 256, 0, stream>>>(h0, h_buf + 65536);  // h_{-1} in buf 1
  hipMemcpyAsync(c_st, c0, (size_t)64 * 1024 * 4, hipMemcpyDeviceToDevice, stream);
  transpose_w<<<dim3(64, 16, 2), 256, 0, stream>>>(wih, whh, wih_t, whh_t);

  for (int t0 = 0; t0 < 512; t0 += W) {
    gemm_xg<<<dim3(32, W / 2), 256, 0, stream>>>(x + (size_t)t0 * 64 * 1024, wih_t, bias, xg);
    int t0c = t0, Wc = W;
    void* args[] = {(void*)&xg,    (void*)&whh_t,  (void*)&h_buf,  (void*)&c_st,
                    (void*)&out_h, (void*)&out_hT, (void*)&out_cT, (void*)&flags,
                    (void*)&t0c,   (void*)&Wc};
    hipLaunchCooperativeKernel((const void*)recur_pers, dim3(512), dim3(256), args, 0,
                               stream);
  }
}

// Round 13
// 4371.849 us; speedup vs baseline: 1.5420x; 1.5420x over previous
//
#include <hip/hip_runtime.h>
#include <stdint.h>

// R13 (base = R11, best at 412us/win; R12's lockstep-co-residency regression
// reverted). Levers on L = chain + tail:
//  - 32 producers per group barrier (was 64): block = 32 units x 4 gates,
//    512 thr, wave = distinct K-slice-128, bfr[4][8] = 128 VGPRs resident.
//  - monotonic flags (flags[bq][un] = t+1, 512B, no re-zero): polls hit hot
//    L3 lines; flags now stored every step incl. window-last (cross-launch).
//  - xg loads issued BEFORE the poll (complete under it); out_h stores issued
//    AFTER the flag store (drain overlaps next phase's poll).
//  - no duplicated h loads (each wave a distinct K-slice): h L3 traffic /2.
//  - dual-stream A/B per block kept from R11 (hides wait under partner phase).
// Protocol (R9-R12-proven): agent h store -> __syncthreads (vmcnt drain) ->
// flag store; consumer: poll flags -> __syncthreads -> agent h load.

typedef unsigned short u16;
typedef __attribute__((ext_vector_type(8))) short bf16x8;
typedef __attribute__((ext_vector_type(2))) uint64_t u64x2;
typedef __attribute__((ext_vector_type(4))) float f32x4;

static __device__ __forceinline__ u16 f2b(float f) {
  uint32_t b = __float_as_uint(f);
  return (u16)((b + 0x7fffu + ((b >> 16) & 1u)) >> 16);  // RNE
}
static __device__ __forceinline__ uint64_t pack4(float4 v) {
  return (uint64_t)f2b(v.x) | ((uint64_t)f2b(v.y) << 16) |
         ((uint64_t)f2b(v.z) << 32) | ((uint64_t)f2b(v.w) << 48);
}
static __device__ __forceinline__ float b2f(u16 u) {
  return __uint_as_float(((uint32_t)u) << 16);
}
static __device__ __forceinline__ float sigm(float x) {
  return 1.0f / (1.0f + __expf(-x));
}
static __device__ __forceinline__ float tanh_(float x) {
  float e = __expf(2.0f * x);
  return 1.0f - 2.0f / (e + 1.0f);
}

// ---------------------------------------------------------------- prep kernels
__global__ __launch_bounds__(256) void transpose_w(const float* __restrict__ Wih,
                                                   const float* __restrict__ Whh,
                                                   u16* __restrict__ Tih,
                                                   u16* __restrict__ Thh) {
  __shared__ float tile[64][65];
  const float* src = blockIdx.z ? Whh : Wih;
  u16* dst = blockIdx.z ? Thh : Tih;
  int k0 = blockIdx.y * 64, n0 = blockIdx.x * 64;
  int tid = threadIdx.x;
#pragma unroll
  for (int i = 0; i < 16; ++i) {
    int idx = i * 256 + tid;
    int kl = idx >> 6, nl = idx & 63;
    tile[kl][nl] = src[(size_t)(k0 + kl) * 4096 + n0 + nl];
  }
  __syncthreads();
#pragma unroll
  for (int i = 0; i < 16; ++i) {
    int idx = i * 256 + tid;
    int nl = idx >> 6, kl = idx & 63;
    dst[(size_t)(n0 + nl) * 1024 + k0 + kl] = f2b(tile[kl][nl]);
  }
}

__global__ __launch_bounds__(256) void convert_h0(const float* __restrict__ h0,
                                                  u16* __restrict__ dst) {
  int i = blockIdx.x * 256 + threadIdx.x;  // 16384 float4s
  float4 v = ((const float4*)h0)[i];
  ((uint64_t*)dst)[i] = pack4(v);
}

// ------------------------------------------------------------------- big GEMM
// C[M][4096] bf16 = A[M][1024] f32 @ Bt[4096][1024]^T + bias. (unchanged, PASS)
__global__ __launch_bounds__(256) void gemm_xg(const float* __restrict__ A,
                                               const u16* __restrict__ Bt,
                                               const float* __restrict__ bias,
                                               u16* __restrict__ C) {
  __shared__ u16 sA[2][128 * 32];
  __shared__ u16 sB[2][128 * 32];
  const int tid = threadIdx.x;
  const int wave = tid >> 6, lane = tid & 63;
  const int bx = blockIdx.x, by = blockIdx.y;
  const int wr = wave >> 1, wc = wave & 1;
  const int lm = lane & 15, ko = (lane >> 4) * 8;

  const int ar = lane >> 1, ac = (lane & 1) * 16;
  const float* gA = A + (size_t)(by * 128 + wave * 32 + ar) * 1024 + ac;
  const u16* gB = Bt + (size_t)(bx * 128 + wave * 32 + (lane >> 2)) * 1024 + (lane & 3) * 8;
  const int bidx = wave * 1024 + (lane >> 2) * 32 + (lane & 3) * 8;

  f32x4 acc[4][4] = {};

  auto stage = [&](int kt, int buf) {
    const u16* gb = gB + kt * 32;
    bf16x8 b0 = *(const bf16x8*)gb;
    bf16x8 b1 = *(const bf16x8*)(gb + 16 * 1024);
    *(bf16x8*)&sB[buf][bidx] = b0;
    *(bf16x8*)&sB[buf][bidx + 512] = b1;
    const float* ga = gA + kt * 32;
    float4 v0 = *(const float4*)(ga + 0);
    float4 v1 = *(const float4*)(ga + 4);
    float4 v2 = *(const float4*)(ga + 8);
    float4 v3 = *(const float4*)(ga + 12);
    uint64_t* la = (uint64_t*)&sA[buf][wave * 1024 + ar * 32 + ac];
    la[0] = pack4(v0);
    la[1] = pack4(v1);
    la[2] = pack4(v2);
    la[3] = pack4(v3);
  };

  stage(0, 0);
  __syncthreads();
  int p = 0;
  for (int kt = 0; kt < 32; ++kt) {
    if (kt < 31) stage(kt + 1, p ^ 1);
    bf16x8 af[4], bfv[4];
#pragma unroll
    for (int i = 0; i < 4; ++i)
      af[i] = *(const bf16x8*)&sA[p][(wr * 64 + i * 16 + lm) * 32 + ko];
#pragma unroll
    for (int j = 0; j < 4; ++j)
      bfv[j] = *(const bf16x8*)&sB[p][(wc * 64 + j * 16 + lm) * 32 + ko];
#pragma unroll
    for (int i = 0; i < 4; ++i)
#pragma unroll
      for (int j = 0; j < 4; ++j)
        acc[i][j] = __builtin_amdgcn_mfma_f32_16x16x32_bf16(af[i], bfv[j], acc[i][j], 0, 0, 0);
    __syncthreads();
    p ^= 1;
  }

  float bj[4];
#pragma unroll
  for (int j = 0; j < 4; ++j)
    bj[j] = bias[bx * 128 + wc * 64 + j * 16 + lm];
#pragma unroll
  for (int i = 0; i < 4; ++i) {
    int row = by * 128 + wr * 64 + i * 16 + (lane >> 4) * 4;
#pragma unroll
    for (int j = 0; j < 4; ++j) {
      int col = bx * 128 + wc * 64 + j * 16 + lm;
#pragma unroll
      for (int r = 0; r < 4; ++r)
        C[(size_t)(row + r) * 4096 + col] = f2b(acc[i][j][r] + bj[j]);
    }
  }
}

// ------------------------------------- persistent dual-stream recurrence
// Grid 64 blocks, block 512 (8 waves). bid: un=bid>>1 (units un*32..+32),
// p=bid&1 -> streams bq {2p, 2p+1}. Block covers 128 gate-cols (4 gates x 32
// units), c_local = gate*32 + ul. Wave w = K-slice [w*128,+128): bfr[kk][nt]
// (32 frags = 128 VGPRs), a[4] distinct per wave (no duplicate h loads).
// Epilogue: all 512 threads own one (row r_b=tid>>5, unit ul=tid&31).
__global__ __launch_bounds__(512, 2) void recur_pers(
    const u16* __restrict__ xg,      // [W][64][4096] bf16, bias already added
    const u16* __restrict__ whh_t,   // [4096][1024] bf16
    u16* __restrict__ h_buf,         // [2][64][1024] bf16 ping-pong
    float* __restrict__ c_st,        // [64][1024] f32
    float* __restrict__ out_h,       // [512][64][1024] f32
    float* __restrict__ out_hT, float* __restrict__ out_cT,
    uint32_t* __restrict__ flags,    // [4][32] u32 MONOTONIC (= done step+1)
    int t0, int W) {
  __shared__ float xchg[8][16][132];  // 67.6KB, padded (2-way banks = free)

  const int tid = threadIdx.x;
  const int wave = tid >> 6, lane = tid & 63;
  const int bid = blockIdx.x;
  const int un = bid >> 1;
  const int p = bid & 1;
  const int lm = lane & 15, ko = (lane >> 4) * 8;

  // ---- W_hh B-frags resident: bfr[kk][nt]; col c_local = nt*16 + lm ----
  bf16x8 bfr[4][8];
#pragma unroll
  for (int nt = 0; nt < 8; ++nt) {
    int c = nt * 16 + lm;  // [0,128): gate = c>>5, ul = c&31
    const u16* bp =
        whh_t + (size_t)((c >> 5) * 1024 + un * 32 + (c & 31)) * 1024 + wave * 128 + ko;
#pragma unroll
    for (int kk = 0; kk < 4; ++kk) bfr[kk][nt] = *(const bf16x8*)(bp + kk * 32);
  }

  // ---- epilogue ownership: all 512 threads -> (row r_b, unit ul) ----
  const int r_b = tid >> 5, ul = tid & 31;
  const int unit = un * 32 + ul;
  const int bA = (2 * p) * 16 + r_b;
  const int bB = (2 * p + 1) * 16 + r_b;
  float cA = c_st[bA * 1024 + unit];
  float cB = c_st[bB * 1024 + unit];

  auto phase = [&](int bq, int b, float& c_val, int ts, int t) {
    // ---- xg loads issued BEFORE the poll: complete during it ----
    const u16* xgp = xg + ((size_t)ts * 64 + b) * 4096 + unit;
    u16 xr0 = xgp[0], xr1 = xgp[1024], xr2 = xgp[2048], xr3 = xgp[3072];

    // ---- poll: 32 producers of this bq done with step t-1 (flag >= t) ----
    {
      const uint32_t* fl = flags + bq * 32;
      if (wave == 7) {
        uint32_t spin = 0;
        for (; spin < (1u << 15); ++spin) {  // bounded: never wedge
          uint32_t v = __hip_atomic_load(fl + (lane & 31), __ATOMIC_RELAXED,
                                         __HIP_MEMORY_SCOPE_AGENT);
          if (__all(v >= (uint32_t)t)) break;
          __builtin_amdgcn_s_sleep(1);
        }
        if (spin >= (1u << 15) && lane == 0)  // sentinel: absmax ~1e6
          out_h[(size_t)t * 65536 + bid] = 1.0e6f;
      }
      __syncthreads();
    }

    // ---- A-frags: distinct K-slice per wave, agent-scope (L3) ----
    const u16* ap = h_buf + (size_t)((t - 1) & 1) * 65536 +
                    (size_t)(bq * 16 + lm) * 1024 + wave * 128 + ko;
    bf16x8 a[4];
#pragma unroll
    for (int kk = 0; kk < 4; ++kk) {
      const uint64_t* pp = (const uint64_t*)(ap + kk * 32);
      u64x2 v;
      v.x = __hip_atomic_load(pp, __ATOMIC_RELAXED, __HIP_MEMORY_SCOPE_AGENT);
      v.y = __hip_atomic_load(pp + 1, __ATOMIC_RELAXED, __HIP_MEMORY_SCOPE_AGENT);
      a[kk] = __builtin_bit_cast(bf16x8, v);
    }

    // ---- 8 independent 4-deep MFMA chains ----
    f32x4 acc[8] = {};
#pragma unroll
    for (int kk = 0; kk < 4; ++kk)
#pragma unroll
      for (int nt = 0; nt < 8; ++nt)
        acc[nt] = __builtin_amdgcn_mfma_f32_16x16x32_bf16(a[kk], bfr[kk][nt], acc[nt], 0, 0, 0);

    {
      int crow = (lane >> 4) * 4;  // C layout: col=lane&15, row=(lane>>4)*4+r
#pragma unroll
      for (int nt = 0; nt < 8; ++nt)
#pragma unroll
        for (int r = 0; r < 4; ++r) xchg[wave][crow + r][nt * 16 + lm] = acc[nt][r];
    }
    __syncthreads();

    // ---- reduce over 8 K-slices + LSTM cell (all 512 threads) ----
    float raw[4];
#pragma unroll
    for (int g = 0; g < 4; ++g) {
      int c = g * 32 + ul;
      float s = xchg[0][r_b][c];
#pragma unroll
      for (int w = 1; w < 8; ++w) s += xchg[w][r_b][c];
      raw[g] = s;
    }
    float ig = sigm(raw[0] + b2f(xr0));
    float fg = sigm(raw[1] + b2f(xr1));
    float gg = tanh_(raw[2] + b2f(xr2));
    float og = sigm(raw[3] + b2f(xr3));
    c_val = fg * c_val + ig * gg;
    float h_new = og * tanh_(c_val);
    {
      uint32_t mine = f2b(h_new);
      uint32_t other = __shfl_xor(mine, 1);
      if ((ul & 1) == 0) {
        uint32_t pairv = mine | (other << 16);
        __hip_atomic_store(
            (uint32_t*)(h_buf + (size_t)(t & 1) * 65536 + (size_t)b * 1024 + unit), pairv,
            __ATOMIC_RELAXED, __HIP_MEMORY_SCOPE_AGENT);
      }
    }

    __syncthreads();  // vmcnt drain: h_buf stores globally visible
    if (tid == 0)
      __hip_atomic_store(flags + bq * 32 + un, (uint32_t)(t + 1), __ATOMIC_RELAXED,
                         __HIP_MEMORY_SCOPE_AGENT);
    // out_h AFTER the flag: its drain overlaps the next phase's poll
    out_h[(size_t)t * 65536 + (size_t)b * 1024 + unit] = h_new;
    if (t == 511) {
      out_hT[b * 1024 + unit] = h_new;
      out_cT[b * 1024 + unit] = c_val;
    }
  };

  for (int ts = 0; ts < W; ++ts) {
    const int t = t0 + ts;
    phase(2 * p, bA, cA, ts, t);
    phase(2 * p + 1, bB, cB, ts, t);
  }

  c_st[bA * 1024 + unit] = cA;
  c_st[bB * 1024 + unit] = cB;
}

// -------------------------------------------------------------------- launch
extern "C" void kernel_launch(void* const* d_in, const int* in_sizes, int n_in,
                              void* d_out, int out_size, void* d_ws, size_t ws_size,
                              hipStream_t stream) {
  const float* x = (const float*)d_in[0];
  const float* h0 = (const float*)d_in[1];
  const float* c0 = (const float*)d_in[2];
  const float* wih = (const float*)d_in[3];
  const float* whh = (const float*)d_in[4];
  const float* bias = (const float*)d_in[5];

  float* out = (float*)d_out;
  float* out_h = out;                              // [512][64][1024]
  float* out_hT = out + (size_t)512 * 64 * 1024;   // [64][1024]
  float* out_cT = out_hT + 64 * 1024;              // [64][1024]

  // adaptive xg window (bf16): W in {64,16,4}
  const size_t fixed = (size_t)2 * 4096 * 1024 * 2   // wih_t + whh_t
                       + (size_t)2 * 64 * 1024 * 2   // h_buf
                       + (size_t)64 * 1024 * 4       // c_state
                       + 4096;                       // flags (512B, padded)
  int W = 64;
  while (W > 4 && fixed + (size_t)W * 64 * 4096 * 2 > ws_size) W >>= 2;

  char* ws = (char*)d_ws;
  u16* wih_t = (u16*)ws;   ws += (size_t)4096 * 1024 * 2;    // 8MB
  u16* whh_t = (u16*)ws;   ws += (size_t)4096 * 1024 * 2;    // 8MB
  u16* xg = (u16*)ws;      ws += (size_t)W * 64 * 4096 * 2;  // <=32MB
  u16* h_buf = (u16*)ws;   ws += (size_t)2 * 64 * 1024 * 2;  // 256KB
  float* c_st = (float*)ws; ws += (size_t)64 * 1024 * 4;     // 256KB
  uint32_t* flags = (uint32_t*)ws;                           // 512B (monotonic)

  hipMemsetAsync(flags, 0, 4096, stream);
  convert_h0<<<64, 256, 0, stream>>>(h0, h_buf + 65536);  // h_{-1} in buf 1
  hipMemcpyAsync(c_st, c0, (size_t)64 * 1024 * 4, hipMemcpyDeviceToDevice, stream);
  transpose_w<<<dim3(64, 16, 2), 256, 0, stream>>>(wih, whh, wih_t, whh_t);

  for (int t0 = 0; t0 < 512; t0 += W) {
    gemm_xg<<<dim3(32, W / 2), 256, 0, stream>>>(x + (size_t)t0 * 64 * 1024, wih_t, bias, xg);
    int t0c = t0, Wc = W;
    void* args[] = {(void*)&xg,    (void*)&whh_t,  (void*)&h_buf,  (void*)&c_st,
                    (void*)&out_h, (void*)&out_hT, (void*)&out_cT, (void*)&flags,
                    (void*)&t0c,   (void*)&Wc};
    hipLaunchCooperativeKernel((const void*)recur_pers, dim3(64), dim3(512), args, 0,
                               stream);
  }
}

// Round 15
// 4014.406 us; speedup vs baseline: 1.6793x; 1.0890x over previous
//
#include <hip/hip_runtime.h>
#include <stdint.h>

// R15 = R14 TAGGED-H protocol + THE FIX: h_tag must be zero-initialized every
// launch. R14 forgot it; harness poisons d_ws with 0xAA => tag 0xAAAAAAAA
// passes every "tag >= t" check, so consumers racing ahead of producer stores
// read poison payload (~0) instead of waiting -> absmax 0.047. Replays would
// similarly see stale tags (harness does not re-poison between replays).
// hipMemsetAsync(h_tag, 0, ...) at launch start fixes both. Protocol proof
// (unchanged): a producer can never be >=2 steps ahead of a still-polling
// same-bq consumer, so the polled buffer holds only tag==t words or stale
// (tag < t) ones; tag >= t filters correctly. One atomic u64 per h-pair fuses
// payload+flag: chain = store -> L3 visibility -> tagged load. No flags, no
// drains, no delegated poll.

typedef unsigned short u16;
typedef __attribute__((ext_vector_type(8))) short bf16x8;
typedef __attribute__((ext_vector_type(2))) uint64_t u64x2;
typedef __attribute__((ext_vector_type(4))) float f32x4;

static __device__ __forceinline__ u16 f2b(float f) {
  uint32_t b = __float_as_uint(f);
  return (u16)((b + 0x7fffu + ((b >> 16) & 1u)) >> 16);  // RNE
}
static __device__ __forceinline__ uint64_t pack4(float4 v) {
  return (uint64_t)f2b(v.x) | ((uint64_t)f2b(v.y) << 16) |
         ((uint64_t)f2b(v.z) << 32) | ((uint64_t)f2b(v.w) << 48);
}
static __device__ __forceinline__ float b2f(u16 u) {
  return __uint_as_float(((uint32_t)u) << 16);
}
static __device__ __forceinline__ float sigm(float x) {
  return 1.0f / (1.0f + __expf(-x));
}
static __device__ __forceinline__ float tanh_(float x) {
  float e = __expf(2.0f * x);
  return 1.0f - 2.0f / (e + 1.0f);
}

// ---------------------------------------------------------------- prep kernels
__global__ __launch_bounds__(256) void transpose_w(const float* __restrict__ Wih,
                                                   const float* __restrict__ Whh,
                                                   u16* __restrict__ Tih,
                                                   u16* __restrict__ Thh) {
  __shared__ float tile[64][65];
  const float* src = blockIdx.z ? Whh : Wih;
  u16* dst = blockIdx.z ? Thh : Tih;
  int k0 = blockIdx.y * 64, n0 = blockIdx.x * 64;
  int tid = threadIdx.x;
#pragma unroll
  for (int i = 0; i < 16; ++i) {
    int idx = i * 256 + tid;
    int kl = idx >> 6, nl = idx & 63;
    tile[kl][nl] = src[(size_t)(k0 + kl) * 4096 + n0 + nl];
  }
  __syncthreads();
#pragma unroll
  for (int i = 0; i < 16; ++i) {
    int idx = i * 256 + tid;
    int nl = idx >> 6, kl = idx & 63;
    dst[(size_t)(n0 + nl) * 1024 + k0 + kl] = f2b(tile[kl][nl]);
  }
}

// h0 [64][1024] f32 -> tagged words (tag 0) in h_tag buf 1
__global__ __launch_bounds__(256) void convert_h0(const float* __restrict__ h0,
                                                  uint64_t* __restrict__ dst) {
  int i = blockIdx.x * 256 + threadIdx.x;  // 32768 words
  float2 v = ((const float2*)h0)[i];
  uint32_t pair = (uint32_t)f2b(v.x) | ((uint32_t)f2b(v.y) << 16);
  dst[i] = (uint64_t)pair;  // tag = 0
}

// ------------------------------------------------------------------- big GEMM
// C[M][4096] bf16 = A[M][1024] f32 @ Bt[4096][1024]^T + bias. (unchanged, PASS)
__global__ __launch_bounds__(256) void gemm_xg(const float* __restrict__ A,
                                               const u16* __restrict__ Bt,
                                               const float* __restrict__ bias,
                                               u16* __restrict__ C) {
  __shared__ u16 sA[2][128 * 32];
  __shared__ u16 sB[2][128 * 32];
  const int tid = threadIdx.x;
  const int wave = tid >> 6, lane = tid & 63;
  const int bx = blockIdx.x, by = blockIdx.y;
  const int wr = wave >> 1, wc = wave & 1;
  const int lm = lane & 15, ko = (lane >> 4) * 8;

  const int ar = lane >> 1, ac = (lane & 1) * 16;
  const float* gA = A + (size_t)(by * 128 + wave * 32 + ar) * 1024 + ac;
  const u16* gB = Bt + (size_t)(bx * 128 + wave * 32 + (lane >> 2)) * 1024 + (lane & 3) * 8;
  const int bidx = wave * 1024 + (lane >> 2) * 32 + (lane & 3) * 8;

  f32x4 acc[4][4] = {};

  auto stage = [&](int kt, int buf) {
    const u16* gb = gB + kt * 32;
    bf16x8 b0 = *(const bf16x8*)gb;
    bf16x8 b1 = *(const bf16x8*)(gb + 16 * 1024);
    *(bf16x8*)&sB[buf][bidx] = b0;
    *(bf16x8*)&sB[buf][bidx + 512] = b1;
    const float* ga = gA + kt * 32;
    float4 v0 = *(const float4*)(ga + 0);
    float4 v1 = *(const float4*)(ga + 4);
    float4 v2 = *(const float4*)(ga + 8);
    float4 v3 = *(const float4*)(ga + 12);
    uint64_t* la = (uint64_t*)&sA[buf][wave * 1024 + ar * 32 + ac];
    la[0] = pack4(v0);
    la[1] = pack4(v1);
    la[2] = pack4(v2);
    la[3] = pack4(v3);
  };

  stage(0, 0);
  __syncthreads();
  int p = 0;
  for (int kt = 0; kt < 32; ++kt) {
    if (kt < 31) stage(kt + 1, p ^ 1);
    bf16x8 af[4], bfv[4];
#pragma unroll
    for (int i = 0; i < 4; ++i)
      af[i] = *(const bf16x8*)&sA[p][(wr * 64 + i * 16 + lm) * 32 + ko];
#pragma unroll
    for (int j = 0; j < 4; ++j)
      bfv[j] = *(const bf16x8*)&sB[p][(wc * 64 + j * 16 + lm) * 32 + ko];
#pragma unroll
    for (int i = 0; i < 4; ++i)
#pragma unroll
      for (int j = 0; j < 4; ++j)
        acc[i][j] = __builtin_amdgcn_mfma_f32_16x16x32_bf16(af[i], bfv[j], acc[i][j], 0, 0, 0);
    __syncthreads();
    p ^= 1;
  }

  float bj[4];
#pragma unroll
  for (int j = 0; j < 4; ++j)
    bj[j] = bias[bx * 128 + wc * 64 + j * 16 + lm];
#pragma unroll
  for (int i = 0; i < 4; ++i) {
    int row = by * 128 + wr * 64 + i * 16 + (lane >> 4) * 4;
#pragma unroll
    for (int j = 0; j < 4; ++j) {
      int col = bx * 128 + wc * 64 + j * 16 + lm;
#pragma unroll
      for (int r = 0; r < 4; ++r)
        C[(size_t)(row + r) * 4096 + col] = f2b(acc[i][j][r] + bj[j]);
    }
  }
}

// --------------------------------------- persistent tagged-h recurrence
// Grid 256 blocks (1/CU), block 512 (8 waves). bid: un=bid&63 (units
// un*16..+16), bq=bid>>6 (batch rows bq*16..+16). 64 gate-cols/block:
// c = nt*16+lm, gate = nt, ucol = c&15. Wave w = K-slice [w*128,+128):
// bfr[kk][nt] 16 frags = 64 VGPRs resident; A-frag = 16 tagged u64 words
// polled directly (tag = producing step + 1, check >= t).
__global__ __launch_bounds__(512, 1) void recur_pers(
    const u16* __restrict__ xg,        // [W][64][4096] bf16, bias added
    const u16* __restrict__ whh_t,     // [4096][1024] bf16
    uint64_t* __restrict__ h_tag,      // [2][64][512] tagged words
    float* __restrict__ c_st,          // [64][1024] f32
    float* __restrict__ out_h,         // [512][64][1024] f32
    float* __restrict__ out_hT, float* __restrict__ out_cT,
    int t0, int W) {
  __shared__ float xchg[8][16][68];  // 34.8KB, padded

  const int tid = threadIdx.x;
  const int wave = tid >> 6, lane = tid & 63;
  const int bid = blockIdx.x;
  const int un = bid & 63;
  const int bq = bid >> 6;
  const int lm = lane & 15, hi = lane >> 4;

  // ---- W_hh B-frags resident: bfr[kk][nt]; row = nt*1024 + un*16 + lm ----
  bf16x8 bfr[4][4];
#pragma unroll
  for (int nt = 0; nt < 4; ++nt) {
    const u16* bp = whh_t + (size_t)(nt * 1024 + un * 16 + lm) * 1024 + wave * 128 + hi * 8;
#pragma unroll
    for (int kk = 0; kk < 4; ++kk) bfr[kk][nt] = *(const bf16x8*)(bp + kk * 32);
  }

  // ---- epilogue ownership: tid<256 -> (row r_b, unit u) ----
  const int r_b = tid >> 4, u = tid & 15;
  const int b = bq * 16 + r_b;
  const int unit = un * 16 + u;
  float c_val = (tid < 256) ? c_st[b * 1024 + unit] : 0.f;

  const int b_row = bq * 16 + lm;  // A-frag batch row for this lane

  for (int ts = 0; ts < W; ++ts) {
    const int t = t0 + ts;

    // ---- xg loads first (independent; complete under the poll) ----
    u16 xr0 = 0, xr1 = 0, xr2 = 0, xr3 = 0;
    if (tid < 256) {
      const u16* xgp = xg + ((size_t)ts * 64 + b) * 4096 + unit;
      xr0 = xgp[0];
      xr1 = xgp[1024];
      xr2 = xgp[2048];
      xr3 = xgp[3072];
    }

    // ---- poll the 16 tagged words of my A-frag (tag >= t) ----
    const uint64_t* hb = h_tag + ((size_t)((t - 1) & 1) * 64 + b_row) * 512 +
                         wave * 64 + hi * 4;
    uint64_t wbuf[16];
    {
      uint32_t spin = 0;
      bool ok = false;
      for (; spin < (1u << 15); ++spin) {  // bounded: never wedge
#pragma unroll
        for (int kk = 0; kk < 4; ++kk)
#pragma unroll
          for (int j = 0; j < 4; ++j)
            wbuf[kk * 4 + j] = __hip_atomic_load(hb + kk * 16 + j, __ATOMIC_RELAXED,
                                                 __HIP_MEMORY_SCOPE_AGENT);
        bool good = true;
#pragma unroll
        for (int i = 0; i < 16; ++i)
          good &= ((uint32_t)(wbuf[i] >> 32) >= (uint32_t)t);
        if (__all(good)) { ok = true; break; }
        __builtin_amdgcn_s_sleep(1);
      }
      if (!ok && lane == 0)  // sentinel: absmax ~1e6 => protocol stall
        out_h[(size_t)t * 65536 + bid] = 1.0e6f;
    }

    // ---- extract payload -> 4 A-frags; 16 MFMAs (4 chains of 4) ----
    f32x4 acc[4] = {};
#pragma unroll
    for (int kk = 0; kk < 4; ++kk) {
      u64x2 v;
      v.x = (uint64_t)(uint32_t)wbuf[kk * 4 + 0] |
            ((uint64_t)(uint32_t)wbuf[kk * 4 + 1] << 32);
      v.y = (uint64_t)(uint32_t)wbuf[kk * 4 + 2] |
            ((uint64_t)(uint32_t)wbuf[kk * 4 + 3] << 32);
      bf16x8 a = __builtin_bit_cast(bf16x8, v);
#pragma unroll
      for (int nt = 0; nt < 4; ++nt)
        acc[nt] = __builtin_amdgcn_mfma_f32_16x16x32_bf16(a, bfr[kk][nt], acc[nt], 0, 0, 0);
    }
    {
      int crow = hi * 4;  // C layout: col=lane&15, row=(lane>>4)*4+r
#pragma unroll
      for (int nt = 0; nt < 4; ++nt)
#pragma unroll
        for (int r = 0; r < 4; ++r) xchg[wave][crow + r][nt * 16 + lm] = acc[nt][r];
    }
    __syncthreads();  // all waves polled + wrote xchg (=> WAR-safe to store h)

    if (tid < 256) {
      float raw[4];
#pragma unroll
      for (int g = 0; g < 4; ++g) {
        int c = g * 16 + u;
        float s = xchg[0][r_b][c];
#pragma unroll
        for (int w = 1; w < 8; ++w) s += xchg[w][r_b][c];
        raw[g] = s;
      }
      float ig = sigm(raw[0] + b2f(xr0));
      float fg = sigm(raw[1] + b2f(xr1));
      float gg = tanh_(raw[2] + b2f(xr2));
      float og = sigm(raw[3] + b2f(xr3));
      c_val = fg * c_val + ig * gg;
      float h_new = og * tanh_(c_val);
      // tagged store: ONE atomic u64 = payload pair | (t+1)<<32
      uint32_t mine = f2b(h_new);
      uint32_t other = __shfl_xor(mine, 1);
      if ((u & 1) == 0) {
        uint64_t word = (uint64_t)(mine | (other << 16)) | ((uint64_t)(uint32_t)(t + 1) << 32);
        __hip_atomic_store(
            h_tag + ((size_t)(t & 1) * 64 + b) * 512 + (unit >> 1), word,
            __ATOMIC_RELAXED, __HIP_MEMORY_SCOPE_AGENT);
      }
      out_h[(size_t)t * 65536 + (size_t)b * 1024 + unit] = h_new;
      if (t == 511) {
        out_hT[b * 1024 + unit] = h_new;
        out_cT[b * 1024 + unit] = c_val;
      }
    }
    __syncthreads();  // xchg WAR: reduce-reads done before next step's writes
  }

  if (tid < 256) c_st[b * 1024 + unit] = c_val;
}

// -------------------------------------------------------------------- launch
extern "C" void kernel_launch(void* const* d_in, const int* in_sizes, int n_in,
                              void* d_out, int out_size, void* d_ws, size_t ws_size,
                              hipStream_t stream) {
  const float* x = (const float*)d_in[0];
  const float* h0 = (const float*)d_in[1];
  const float* c0 = (const float*)d_in[2];
  const float* wih = (const float*)d_in[3];
  const float* whh = (const float*)d_in[4];
  const float* bias = (const float*)d_in[5];

  float* out = (float*)d_out;
  float* out_h = out;                              // [512][64][1024]
  float* out_hT = out + (size_t)512 * 64 * 1024;   // [64][1024]
  float* out_cT = out_hT + 64 * 1024;              // [64][1024]

  // adaptive xg window (bf16): W in {64,16,4}
  const size_t fixed = (size_t)2 * 4096 * 1024 * 2    // wih_t + whh_t
                       + (size_t)2 * 64 * 512 * 8     // h_tag (512KB)
                       + (size_t)64 * 1024 * 4;       // c_state
  int W = 64;
  while (W > 4 && fixed + (size_t)W * 64 * 4096 * 2 > ws_size) W >>= 2;

  char* ws = (char*)d_ws;
  u16* wih_t = (u16*)ws;     ws += (size_t)4096 * 1024 * 2;    // 8MB
  u16* whh_t = (u16*)ws;     ws += (size_t)4096 * 1024 * 2;    // 8MB
  u16* xg = (u16*)ws;        ws += (size_t)W * 64 * 4096 * 2;  // <=32MB
  uint64_t* h_tag = (uint64_t*)ws; ws += (size_t)2 * 64 * 512 * 8;  // 512KB
  float* c_st = (float*)ws;                                    // 256KB

  // THE FIX: tags must start below any future t (harness poisons ws with 0xAA
  // => tag 0xAAAAAAAA passes every check; replays would see stale tags too).
  hipMemsetAsync(h_tag, 0, (size_t)2 * 64 * 512 * 8, stream);
  convert_h0<<<128, 256, 0, stream>>>(h0, h_tag + (size_t)64 * 512);  // buf 1
  hipMemcpyAsync(c_st, c0, (size_t)64 * 1024 * 4, hipMemcpyDeviceToDevice, stream);
  transpose_w<<<dim3(64, 16, 2), 256, 0, stream>>>(wih, whh, wih_t, whh_t);

  for (int t0 = 0; t0 < 512; t0 += W) {
    gemm_xg<<<dim3(32, W / 2), 256, 0, stream>>>(x + (size_t)t0 * 64 * 1024, wih_t, bias, xg);
    int t0c = t0, Wc = W;
    void* args[] = {(void*)&xg,    (void*)&whh_t,  (void*)&h_tag, (void*)&c_st,
                    (void*)&out_h, (void*)&out_hT, (void*)&out_cT,
                    (void*)&t0c,   (void*)&Wc};
    hipLaunchCooperativeKernel((const void*)recur_pers, dim3(256), dim3(512), args, 0,
                               stream);
  }
}